// Round 1
// baseline (4500.544 us; speedup 1.0000x reference)
//
#include <hip/hip_runtime.h>
#include <hip/hip_bf16.h>

#define LEN   4096
#define EMB   300
#define HALF  256
#define G4    1024   // 4*HALF
#define HID   512
#define OUT_N 20

#if defined(__has_builtin)
#  if __has_builtin(__builtin_amdgcn_sdot4)
#    define HAVE_SDOT4 1
#  endif
#  if __has_builtin(__builtin_amdgcn_rcpf)
#    define RCPF(x) __builtin_amdgcn_rcpf(x)
#  endif
#endif
#ifndef RCPF
#  define RCPF(x) (1.0f/(x))
#endif

__device__ __forceinline__ int dot4(int a, int b, int c){
#ifdef HAVE_SDOT4
  return __builtin_amdgcn_sdot4(a, b, c, false);
#else
  c += (int)(signed char)(a)     * (int)(signed char)(b);
  c += (int)(signed char)(a>>8)  * (int)(signed char)(b>>8);
  c += (int)(signed char)(a>>16) * (int)(signed char)(b>>16);
  c += (int)(a>>24)              * (int)(b>>24);
  return c;
#endif
}

__device__ __forceinline__ float sigm_(float x){ return RCPF(1.f + __expf(-x)); }
__device__ __forceinline__ float tanh_(float x){ return 2.f*RCPF(1.f + __expf(-2.f*x)) - 1.f; }

// ---------------- prep: quantize Whh rows to i8 + bias sums -----------------
__global__ void prep_quant(const float* __restrict__ WhhF, const float* __restrict__ WhhB,
    const float* __restrict__ bihF, const float* __restrict__ bhhF,
    const float* __restrict__ bihB, const float* __restrict__ bhhB,
    signed char* __restrict__ Wq, float* __restrict__ wsc, float* __restrict__ bsum)
{
  int r = blockIdx.x*256 + threadIdx.x;
  if (r >= 2*G4) return;
  int dir = r >> 10, row = r & 1023;
  const float* Wr = (dir ? WhhB : WhhF) + (size_t)row*HALF;
  float m = 0.f;
  for (int k=0;k<HALF;k++) m = fmaxf(m, fabsf(Wr[k]));
  float inv = 127.f / fmaxf(m, 1e-30f);
  signed char* q = Wq + (size_t)r*HALF;
  for (int k=0;k<HALF;k++){
    int v = __float2int_rn(Wr[k]*inv);
    v = v>127?127:(v<-127?-127:v);
    q[k] = (signed char)v;
  }
  wsc[r]  = (m/127.f)*(1.f/127.f);        // scale for (i32 dot) -> f32
  bsum[r] = dir ? (bihB[row]+bhhB[row]) : (bihF[row]+bhhF[row]);
}

// ---------------- Wv_ae = AE @ W_v_a^T + b_v_a  [20,512] --------------------
__global__ void wv_kernel(const float* __restrict__ AE, const float* __restrict__ Wv,
                          const float* __restrict__ bv, float* __restrict__ WvAE)
{
  __shared__ float ae[EMB];
  const int o = blockIdx.x, tid = threadIdx.x;
  for (int k=tid;k<EMB;k+=256) ae[k] = AE[(size_t)o*EMB+k];
  __syncthreads();
  for (int j=tid;j<HID;j+=256){
    const float* wr = Wv + (size_t)j*EMB;
    float d = 0.f;
    for (int k=0;k<EMB;k++) d += ae[k]*wr[k];
    WvAE[(size_t)o*HID + j] = d + bv[j];
  }
}

// ---- generic C[M,N] = A[idx(m),:K] * B[n,:K]^T + bias[n]; out f32 or bf16 ---
__global__ __launch_bounds__(256) void gemm_tn(
    const float* __restrict__ A, int lda, const int* __restrict__ idx,
    const float* __restrict__ B, int ldb, const float* __restrict__ bias,
    float* __restrict__ Cf, __hip_bfloat16* __restrict__ Cb, int ldc,
    int M, int N, int K)
{
  __shared__ __align__(16) float As[16][68];
  __shared__ __align__(16) float Bs[16][68];
  const int tid = threadIdx.x;
  const int bm = blockIdx.x<<6, bn = blockIdx.y<<6;
  const int lm = tid>>2;            // 0..63 row loaded by this thread
  const int lk = (tid&3)<<2;        // 0,4,8,12 k offset
  const int ty = tid>>4, tx = tid&15;
  int arow = bm + lm;
  if (idx) arow = idx[arow];
  const float* Ap = A + (size_t)arow*lda + lk;
  const float* Bp = B + (size_t)(bn+lm)*ldb + lk;
  float acc[4][4];
  #pragma unroll
  for (int i=0;i<4;i++)
    #pragma unroll
    for (int j=0;j<4;j++) acc[i][j]=0.f;

  for (int k0=0;k0<K;k0+=16){
    float4 av, bv;
    if (k0+16 <= K){
      av = *(const float4*)(Ap+k0);
      bv = *(const float4*)(Bp+k0);
    } else {
      float a0[4], b0[4];
      #pragma unroll
      for (int j=0;j<4;j++){
        int kk = k0+lk+j;
        a0[j] = (kk<K)? Ap[k0+j] : 0.f;
        b0[j] = (kk<K)? Bp[k0+j] : 0.f;
      }
      av = make_float4(a0[0],a0[1],a0[2],a0[3]);
      bv = make_float4(b0[0],b0[1],b0[2],b0[3]);
    }
    __syncthreads();
    As[lk+0][lm]=av.x; As[lk+1][lm]=av.y; As[lk+2][lm]=av.z; As[lk+3][lm]=av.w;
    Bs[lk+0][lm]=bv.x; Bs[lk+1][lm]=bv.y; Bs[lk+2][lm]=bv.z; Bs[lk+3][lm]=bv.w;
    __syncthreads();
    #pragma unroll
    for (int kk=0;kk<16;kk++){
      const float4 a = *(const float4*)(&As[kk][ty<<2]);
      const float4 b = *(const float4*)(&Bs[kk][tx<<2]);
      acc[0][0]+=a.x*b.x; acc[0][1]+=a.x*b.y; acc[0][2]+=a.x*b.z; acc[0][3]+=a.x*b.w;
      acc[1][0]+=a.y*b.x; acc[1][1]+=a.y*b.y; acc[1][2]+=a.y*b.z; acc[1][3]+=a.y*b.w;
      acc[2][0]+=a.z*b.x; acc[2][1]+=a.z*b.y; acc[2][2]+=a.z*b.z; acc[2][3]+=a.z*b.w;
      acc[3][0]+=a.w*b.x; acc[3][1]+=a.w*b.y; acc[3][2]+=a.w*b.z; acc[3][3]+=a.w*b.w;
    }
  }
  const int cm = bm+(ty<<2), cn = bn+(tx<<2);
  #pragma unroll
  for (int i=0;i<4;i++){
    #pragma unroll
    for (int j=0;j<4;j++){
      float v = acc[i][j] + (bias ? bias[cn+j] : 0.f);
      if (Cb) Cb[(size_t)(cm+i)*ldc + cn+j] = __float2bfloat16(v);
      else    Cf[(size_t)(cm+i)*ldc + cn+j] = v;
    }
  }
}

// -------------------- persistent bidirectional LSTM scan --------------------
// grid = 2 blocks (dir 0 fwd, dir 1 bwd), 1024 threads: thread r owns row r of
// Whh (256 i8 weights in 64 VGPRs). h quantized to i8 in LDS each step.
__global__ __launch_bounds__(1024, 4) void lstm_scan(
    const __hip_bfloat16* __restrict__ preF,
    const __hip_bfloat16* __restrict__ preB,
    const signed char* __restrict__ Wq,
    const float* __restrict__ wsc,
    float* __restrict__ hs, float* __restrict__ ht)
{
  const int dir = blockIdx.x;
  const int tid = threadIdx.x;
  __shared__ int4 hq4[16];          // 64 bytes*... 256 i8 h values
  __shared__ float gates[G4];
  int w[64];
  {
    const int4* wp = (const int4*)(Wq + ((size_t)(dir*G4 + tid))*HALF);
    #pragma unroll
    for (int i=0;i<16;i++){
      int4 v = wp[i];
      w[4*i+0]=v.x; w[4*i+1]=v.y; w[4*i+2]=v.z; w[4*i+3]=v.w;
    }
  }
  const float scale = wsc[dir*G4 + tid];
  const __hip_bfloat16* pre = dir ? preB : preF;
  const int t0 = dir ? (LEN-1) : 0;
  const int pstep = dir ? -G4 : G4;
  if (tid < 16) hq4[tid] = make_int4(0,0,0,0);
  float c = 0.f;
  const __hip_bfloat16* pp = pre + (size_t)t0*G4 + tid;
  float pv = __bfloat162float(*pp);
  __syncthreads();
  const int grp = tid >> 8;   // 0:i 1:f 2:g~ 3:o (wave-uniform)
  for (int s=0;s<LEN;s++){
    float pnext = 0.f;
    if (s < LEN-1){ pp += pstep; pnext = __bfloat162float(*pp); }
    int acc4 = 0;
    #pragma unroll
    for (int i=0;i<16;i++){
      int4 hv = hq4[i];
      acc4 = dot4(w[4*i+0], hv.x, acc4);
      acc4 = dot4(w[4*i+1], hv.y, acc4);
      acc4 = dot4(w[4*i+2], hv.z, acc4);
      acc4 = dot4(w[4*i+3], hv.w, acc4);
    }
    float g = pv + (float)acc4 * scale;
    float e = __expf( (grp==2) ? (-2.f*g) : (-g) );
    float y = RCPF(1.f + e);
    float a = (grp==2) ? (2.f*y - 1.f) : y;    // tanh or sigmoid
    gates[tid] = a;
    __syncthreads();
    if (tid < HALF){
      const int t = dir ? (LEN-1-s) : s;
      float ig = gates[tid], fg = gates[HALF+tid];
      float gg = gates[2*HALF+tid], og = gates[3*HALF+tid];
      c = fg*c + ig*gg;
      float h = og * tanh_(c);
      hs[(size_t)t*HID + dir*HALF + tid] = h;
      int q = __float2int_rn(h * 127.f);
      ((signed char*)hq4)[tid] = (signed char)q;
      if (s == LEN-1) ht[dir*HALF + tid] = h;
    }
    pv = pnext;
    __syncthreads();
  }
}

// ---------------- xw = ht @ W_x_a^T + b_x_a [512] ---------------------------
__global__ __launch_bounds__(512) void xw_kernel(const float* __restrict__ ht,
    const float* __restrict__ Wx, const float* __restrict__ bx, float* __restrict__ xw)
{
  __shared__ float h[HID];
  const int tid = threadIdx.x;
  h[tid] = ht[tid];
  __syncthreads();
  const float* wr = Wx + (size_t)tid*HID;
  float d = 0.f;
  for (int k=0;k<HID;k++) d += h[k]*wr[k];
  xw[tid] = d + bx[tid];
}

// ------- scores[o,l] = w_a . tanh(Wh_out[l] + Wv_ae[o]) + b_w_a -------------
__global__ __launch_bounds__(256) void scores_kernel(
    const float* __restrict__ WhOut, const float* __restrict__ WvAE,
    const float* __restrict__ wa, const float* __restrict__ bwa,
    float* __restrict__ scores)
{
  __shared__ float red[4];
  const int l = blockIdx.x, tid = threadIdx.x;
  const int lane = tid & 63, wv = tid >> 6;
  const float wl0 = WhOut[(size_t)l*HID + tid];
  const float wl1 = WhOut[(size_t)l*HID + 256 + tid];
  const float wa0 = wa[tid], wa1 = wa[256+tid];
  const float bb = bwa[0];
  for (int o=0;o<OUT_N;o++){
    float v = wa0*tanh_(wl0 + WvAE[o*HID+tid]) + wa1*tanh_(wl1 + WvAE[o*HID+256+tid]);
    #pragma unroll
    for (int m=32;m;m>>=1) v += __shfl_xor(v, m, 64);
    if (lane==0) red[wv] = v;
    __syncthreads();
    if (tid==0) scores[(size_t)o*LEN + l] = red[0]+red[1]+red[2]+red[3] + bb;
    __syncthreads();
  }
}

// ------- softmax over l (per o) + r[o] = weights @ output2 ------------------
__global__ __launch_bounds__(512) void softmax_wsum(
    const float* __restrict__ scores, const float* __restrict__ hs, float* __restrict__ ratt)
{
  __shared__ float sm[LEN];
  __shared__ float red[8];
  __shared__ float bc[2];
  const int o = blockIdx.x, tid = threadIdx.x;
  const int lane = tid & 63, wv = tid >> 6;
  for (int l=tid;l<LEN;l+=512) sm[l] = scores[(size_t)o*LEN + l];
  __syncthreads();
  float mx = -1e30f;
  for (int l=tid;l<LEN;l+=512) mx = fmaxf(mx, sm[l]);
  #pragma unroll
  for (int m=32;m;m>>=1) mx = fmaxf(mx, __shfl_xor(mx, m, 64));
  if (lane==0) red[wv] = mx;
  __syncthreads();
  if (tid==0){ float m0=red[0]; for (int i=1;i<8;i++) m0=fmaxf(m0,red[i]); bc[0]=m0; }
  __syncthreads();
  const float m0 = bc[0];
  float s = 0.f;
  for (int l=tid;l<LEN;l+=512){ float e = __expf(sm[l]-m0); sm[l]=e; s+=e; }
  #pragma unroll
  for (int m=32;m;m>>=1) s += __shfl_xor(s, m, 64);
  if (lane==0) red[wv] = s;
  __syncthreads();
  if (tid==0){ float z=0.f; for (int i=0;i<8;i++) z+=red[i]; bc[1] = 1.f/z; }
  __syncthreads();
  const float rz = bc[1];
  float acc = 0.f;
  const float* hp = hs + tid;
  for (int l=0;l<LEN;l++) acc += sm[l]*hp[(size_t)l*HID];
  ratt[(size_t)o*HID + tid] = acc*rz;
}

// ------- out[o] = sigmoid( dec_W[o] . tanh(r W_p^T + b_p + xw) + dec_b ) ----
__global__ __launch_bounds__(256) void final_kernel(
    const float* __restrict__ ratt, const float* __restrict__ Wp, const float* __restrict__ bp,
    const float* __restrict__ xw, const float* __restrict__ decW, const float* __restrict__ decb,
    float* __restrict__ outp)
{
  __shared__ float rv[HID];
  __shared__ float rr[HID];
  __shared__ float red[4];
  const int o = blockIdx.x, tid = threadIdx.x;
  const int lane = tid & 63, wv = tid >> 6;
  rv[tid]     = ratt[(size_t)o*HID + tid];
  rv[256+tid] = ratt[(size_t)o*HID + 256 + tid];
  __syncthreads();
  #pragma unroll
  for (int jj=0;jj<2;jj++){
    int j = tid + jj*256;
    const float* wr = Wp + (size_t)j*HID;
    float d = 0.f;
    for (int k=0;k<HID;k++) d += rv[k]*wr[k];
    rr[j] = tanh_(d + bp[j] + xw[j]);
  }
  __syncthreads();
  float v = rr[tid]*decW[(size_t)o*HID+tid] + rr[256+tid]*decW[(size_t)o*HID+256+tid];
  #pragma unroll
  for (int m=32;m;m>>=1) v += __shfl_xor(v, m, 64);
  if (lane==0) red[wv] = v;
  __syncthreads();
  if (tid==0) outp[o] = sigm_(red[0]+red[1]+red[2]+red[3] + decb[o]);
}

// ---------------------------------------------------------------------------
extern "C" void kernel_launch(void* const* d_in, const int* in_sizes, int n_in,
                              void* d_out, int out_size, void* d_ws, size_t ws_size,
                              hipStream_t stream)
{
  (void)in_sizes; (void)n_in; (void)out_size; (void)ws_size;
  const int*   sent  = (const int*)  d_in[0];
  const float* embed = (const float*)d_in[1];
  const float* WihF  = (const float*)d_in[2];
  const float* WhhF  = (const float*)d_in[3];
  const float* bihF  = (const float*)d_in[4];
  const float* bhhF  = (const float*)d_in[5];
  const float* WihB  = (const float*)d_in[6];
  const float* WhhB  = (const float*)d_in[7];
  const float* bihB  = (const float*)d_in[8];
  const float* bhhB  = (const float*)d_in[9];
  const float* AE    = (const float*)d_in[10];
  const float* W_h   = (const float*)d_in[11];
  const float* b_h   = (const float*)d_in[12];
  const float* W_v   = (const float*)d_in[13];
  const float* b_v   = (const float*)d_in[14];
  const float* w_a   = (const float*)d_in[15];
  const float* b_w   = (const float*)d_in[16];
  const float* W_p   = (const float*)d_in[17];
  const float* b_p   = (const float*)d_in[18];
  const float* W_x   = (const float*)d_in[19];
  const float* b_x   = (const float*)d_in[20];
  const float* decW  = (const float*)d_in[21];
  const float* decb  = (const float*)d_in[22];
  float* outp = (float*)d_out;

  char* ws = (char*)d_ws;
  size_t off = 0;
  auto alloc = [&](size_t n){ size_t p = off; off += (n + 255) & ~(size_t)255; return p; };
  __hip_bfloat16* preF  = (__hip_bfloat16*)(ws + alloc((size_t)LEN*G4*2));
  __hip_bfloat16* preB  = (__hip_bfloat16*)(ws + alloc((size_t)LEN*G4*2));
  float*          hsbuf = (float*)        (ws + alloc((size_t)LEN*HID*4));
  float*          WhOut = (float*)        (ws + alloc((size_t)LEN*HID*4));
  signed char*    Wq    = (signed char*)  (ws + alloc((size_t)2*G4*HALF));
  float*          wsc   = (float*)        (ws + alloc((size_t)2*G4*4));
  float*          bsum  = (float*)        (ws + alloc((size_t)2*G4*4));
  float*          htv   = (float*)        (ws + alloc((size_t)HID*4));
  float*          WvAE  = (float*)        (ws + alloc((size_t)OUT_N*HID*4));
  float*          xw    = (float*)        (ws + alloc((size_t)HID*4));
  float*          scor  = (float*)        (ws + alloc((size_t)OUT_N*LEN*4));
  float*          ratt  = (float*)        (ws + alloc((size_t)OUT_N*HID*4));

  // prep
  prep_quant<<<8, 256, 0, stream>>>(WhhF, WhhB, bihF, bhhF, bihB, bhhB, Wq, wsc, bsum);
  wv_kernel<<<OUT_N, 256, 0, stream>>>(AE, W_v, b_v, WvAE);

  // pre = gather(embed, sent) @ Wih^T + (bih+bhh), bf16
  gemm_tn<<<dim3(LEN/64, G4/64), 256, 0, stream>>>(
      embed, EMB, sent, WihF, EMB, bsum,        nullptr, preF, G4, LEN, G4, EMB);
  gemm_tn<<<dim3(LEN/64, G4/64), 256, 0, stream>>>(
      embed, EMB, sent, WihB, EMB, bsum + G4,   nullptr, preB, G4, LEN, G4, EMB);

  // sequential bidirectional scan (2 persistent blocks)
  lstm_scan<<<2, 1024, 0, stream>>>(preF, preB, Wq, wsc, hsbuf, htv);

  // Wh_out = output2 @ W_h_a^T + b_h_a
  gemm_tn<<<dim3(LEN/64, HID/64), 256, 0, stream>>>(
      hsbuf, HID, nullptr, W_h, HID, b_h, WhOut, nullptr, HID, LEN, HID, HID);

  xw_kernel<<<1, 512, 0, stream>>>(htv, W_x, b_x, xw);
  scores_kernel<<<LEN, 256, 0, stream>>>(WhOut, WvAE, w_a, b_w, scor);
  softmax_wsum<<<OUT_N, 512, 0, stream>>>(scor, hsbuf, ratt);
  final_kernel<<<OUT_N, 256, 0, stream>>>(ratt, W_p, b_p, xw, decW, decb, outp);
}